// Round 13
// baseline (131.776 us; speedup 1.0000x reference)
//
#include <hip/hip_runtime.h>
#include <math.h>

#define SRATE   24000.0
#define NB      8
#define NT      48000
#define NH      60
#define NC      100
#define NFMT    5
#define CTS     64
#define NCH     (NT / CTS)       // 750 chunks per batch (= waves per batch)
#define TWO_PI  6.283185307179586476925286766559
#define PSC     (1.0f / 1024.0f) // exact 2^-10 prescale
#define NYQS    11.71875f        // 12000 * 2^-10
#define NREP    4                // DIAGNOSTIC: repeat kernel body 4x

typedef float v2f __attribute__((ext_vector_type(2)));

// ---------------- kernel 1: per-chunk f0 sums (double) ----------------
__global__ __launch_bounds__(256) void k_partial(const float* __restrict__ f0,
                                                 double* __restrict__ part) {
    int b = blockIdx.y;
    int ch = blockIdx.x * 4 + (threadIdx.x >> 6);
    int lane = threadIdx.x & 63;
    if (ch < NCH) {
        int t = ch * CTS + lane;
        double q = (double)f0[b * NT + t];
        #pragma unroll
        for (int off = 32; off > 0; off >>= 1)
            q += __shfl_down(q, off, 64);
        if (lane == 0) part[b * NCH + ch] = q;
    }
}

// ---------------- kernel 2: main synthesis (4x diagnostic repeat) ----------
__global__ __launch_bounds__(256, 4) void k_main(const float* __restrict__ f0,
                                                 const float* __restrict__ amps,
                                                 const float* __restrict__ ffq,
                                                 const float* __restrict__ fbw,
                                                 const float* __restrict__ fam,
                                                 const float* __restrict__ initp,
                                                 const double* __restrict__ part,
                                                 float* __restrict__ out) {
    int b = blockIdx.y;
    int ch = blockIdx.x * 4 + (threadIdx.x >> 6);
    int lane = threadIdx.x & 63;
    if (ch >= NCH) return;
    int t0 = ch * CTS;
    int g0 = lane >> 2, j = lane & 3;
    const float4 f4z = make_float4(0.f, 0.f, 0.f, 0.f);
    const float* ab = amps + (size_t)b * NT * NH;

    #define AMPLD(S0, S1, S2, S3, p)                                          \
        { const float4* rr =                                                  \
              (const float4*)(ab + (size_t)(t0 + (p) * 16 + g0) * NH);        \
          S0 = rr[j]; S1 = rr[4 + j]; S2 = rr[8 + j];                         \
          S3 = (j < 3) ? rr[12 + j] : f4z; }

    #pragma unroll 1
    for (int rep = 0; rep < NREP; ++rep) {
        // ---- amp loads for passes 0,1 ----
        float4 A0, A1, A2, A3, B0, B1, B2, B3;
        AMPLD(A0, A1, A2, A3, 0)
        AMPLD(B0, B1, B2, B3, 1)

        // ---- preamble: prefix reduce, final phase, scan, lerp ----
        const double* pb = part + b * NCH;
        double sl = 0.0;
        #pragma unroll
        for (int k = 0; k < 12; ++k) {
            int idx = k * 64 + lane;
            double v = (idx < NCH) ? pb[idx] : 0.0;
            if (idx < ch) sl += v;
        }
        #pragma unroll
        for (int off = 1; off < 64; off <<= 1)
            sl += __shfl_xor(sl, off, 64);

        double initrev = (double)initp[b] * (1.0 / TWO_PI);

        if (ch == 0) {
            double sa = 0.0;
            #pragma unroll
            for (int k = 0; k < 12; ++k) {
                int idx = k * 64 + lane;
                if (idx < NCH) sa += pb[idx];
            }
            #pragma unroll
            for (int off = 1; off < 64; off <<= 1)
                sa += __shfl_xor(sa, off, 64);
            if (lane == 0) {
                double rv = sa * (1.0 / SRATE) + initrev;
                out[NB * NT + b] = (float)((rv - floor(rv)) * TWO_PI);
            }
        }

        double pfrac = sl * (1.0 / SRATE) + initrev;
        float prefF = (float)(pfrac - floor(pfrac));     // wave-uniform

        float f0v = f0[b * NT + t0 + lane];
        float incf = f0v;
        #pragma unroll
        for (int off = 1; off < 64; off <<= 1) {
            float n = __shfl_up(incf, off, 64);
            if (lane >= off) incf += n;
        }
        float rev_l = __builtin_amdgcn_fractf(prefF + incf * (1.0f / 24000.0f));
        float f0s_l = f0v * PSC;

        double srcd = (double)(t0 + lane) * (99.0 / 47999.0);
        int i0 = (int)srcd;
        if (i0 > NC - 2) i0 = NC - 2;
        float frac = (float)(srcd - (double)i0);
        float omf = 1.0f - frac;
        const float* Fq = ffq + (b * NC + i0) * NFMT;
        const float* Bw = fbw + (b * NC + i0) * NFMT;
        const float* Am = fam + (b * NC + i0) * NFMT;
        float fqs[NFMT], c1s[NFMT], c2s[NFMT];
        #pragma unroll
        for (int f = 0; f < NFMT; ++f) {
            float fqv = Fq[f] * omf + Fq[NFMT + f] * frac;
            float bwv = Bw[f] * omf + Bw[NFMT + f] * frac;
            float amv = Am[f] * omf + Am[NFMT + f] * frac;
            float bws = bwv * PSC;
            fqs[f] = fqv * PSC;
            c2s[f] = bws * bws;
            c1s[f] = amv * c2s[f];
        }

        auto do_pass = [&](int p, float4 q0, float4 q1, float4 q2, float4 q3) {
            int gp = (p << 4) + g0;
            float f0s   = __shfl(f0s_l, gp, 64);
            float rev_g = __shfl(rev_l, gp, 64);
            float fq[NFMT], c1[NFMT], c2[NFMT];
            #pragma unroll
            for (int f = 0; f < NFMT; ++f) {
                fq[f] = __shfl(fqs[f], gp, 64);
                c1[f] = __shfl(c1s[f], gp, 64);
                c2[f] = __shfl(c2s[f], gp, 64);
            }
            float hb = (float)(j << 2);
            auto sd = [&](float k) {
                return __builtin_amdgcn_sinf(
                    __builtin_amdgcn_fractf((hb + k) * rev_g));
            };
            v2f s01 = {sd(1.0f),  sd(2.0f)};
            v2f s23 = {sd(3.0f),  sd(4.0f)};
            v2f s45 = {sd(17.0f), sd(18.0f)};
            v2f s67 = {sd(19.0f), sd(20.0f)};
            float c16 = __builtin_amdgcn_cosf(
                __builtin_amdgcn_fractf(16.0f * rev_g));
            v2f cv = {2.0f * c16, 2.0f * c16};
            v2f s89 = cv * s45 - s01;
            v2f sAB = cv * s67 - s23;
            v2f sCD = cv * s89 - s45;
            v2f sEF = cv * sAB - s67;
            v2f acc2 = {0.0f, 0.0f};
            auto pairf = [&](float h1, v2f sn, float a0, float a1) {
                v2f hfl = {h1, h1 + 1.0f};
                v2f hs = f0s * hfl;
                v2f pN = {1.0f, 1.0f}, pD = {1.0f, 1.0f};
                #pragma unroll
                for (int f = 0; f < NFMT; ++f) {
                    v2f d = hs - fq[f];
                    v2f e = d * d + c2[f];
                    pN *= e + c1[f];
                    pD *= e;
                }
                float R = __builtin_amdgcn_rcpf(pD.x * pD.y);
                v2f fac = {pN.x * pD.y * R, pN.y * pD.x * R};
                v2f fm;
                fm.x = (hs.x < NYQS) ? fac.x : 0.0f;
                fm.y = (hs.y < NYQS) ? fac.y : 0.0f;
                v2f aa = {a0, a1};
                acc2 += (sn * aa) * fm;
            };
            pairf(hb + 1.0f,  s01, q0.x, q0.y);
            pairf(hb + 3.0f,  s23, q0.z, q0.w);
            pairf(hb + 17.0f, s45, q1.x, q1.y);
            pairf(hb + 19.0f, s67, q1.z, q1.w);
            pairf(hb + 33.0f, s89, q2.x, q2.y);
            pairf(hb + 35.0f, sAB, q2.z, q2.w);
            pairf(hb + 49.0f, sCD, q3.x, q3.y);
            pairf(hb + 51.0f, sEF, q3.z, q3.w);
            float acc = acc2.x + acc2.y;
            acc += __shfl_xor(acc, 1, 64);
            acc += __shfl_xor(acc, 2, 64);
            if (j == 0) {
                if (!(f0s > 0.0f)) acc = 0.0f;
                out[b * NT + t0 + (p << 4) + g0] = acc;
            }
        };

        do_pass(0, A0, A1, A2, A3);
        AMPLD(A0, A1, A2, A3, 2)
        do_pass(1, B0, B1, B2, B3);
        AMPLD(B0, B1, B2, B3, 3)
        do_pass(2, A0, A1, A2, A3);
        do_pass(3, B0, B1, B2, B3);

        asm volatile("" ::: "memory");   // keep repeats distinct (no CSE/hoist)
    }
    #undef AMPLD
}

extern "C" void kernel_launch(void* const* d_in, const int* in_sizes, int n_in,
                              void* d_out, int out_size, void* d_ws, size_t ws_size,
                              hipStream_t stream) {
    const float* f0    = (const float*)d_in[0];
    const float* amps  = (const float*)d_in[1];
    const float* ffq   = (const float*)d_in[2];
    const float* fbw   = (const float*)d_in[3];
    const float* fam   = (const float*)d_in[4];
    const float* initp = (const float*)d_in[5];
    float* out = (float*)d_out;

    double* part = (double*)d_ws;                    // NB*NCH doubles (48 KB)

    dim3 gchunk((NCH + 3) / 4, NB);
    k_partial<<<gchunk, 256, 0, stream>>>(f0, part);
    k_main<<<gchunk, 256, 0, stream>>>(f0, amps, ffq, fbw, fam, initp, part, out);
}

// Round 14
// 32.846 us; speedup vs baseline: 4.0120x; 4.0120x over previous
//
#include <hip/hip_runtime.h>
#include <math.h>

#define SRATE   24000.0
#define NB      8
#define NT      48000
#define NH      60
#define NC      100
#define NFMT    5
#define CTS     64
#define NCH     (NT / CTS)       // 750 chunks per batch (= waves per batch)
#define TWO_PI  6.283185307179586476925286766559
#define PSC     (1.0f / 1024.0f) // exact 2^-10 prescale
#define NYQS    11.71875f        // 12000 * 2^-10

typedef float v2f __attribute__((ext_vector_type(2)));

// ---------------- kernel 1: per-chunk f0 sums (double) ----------------
__global__ __launch_bounds__(256) void k_partial(const float* __restrict__ f0,
                                                 double* __restrict__ part) {
    int b = blockIdx.y;
    int ch = blockIdx.x * 4 + (threadIdx.x >> 6);
    int lane = threadIdx.x & 63;
    if (ch < NCH) {
        int t = ch * CTS + lane;
        double q = (double)f0[b * NT + t];
        #pragma unroll
        for (int off = 32; off > 0; off >>= 1)
            q += __shfl_down(q, off, 64);
        if (lane == 0) part[b * NCH + ch] = q;
    }
}

// ---------------- kernel 2: main synthesis ----------------
// R12 structure, but NO min-waves launch_bounds hint: R13's diagnostic showed
// the constrained allocator picked 64 VGPR and spilled ~22 MB/rep to scratch
// (WRITE_SIZE smoking gun). Let the allocator keep the ~90-reg live set in
// registers (4-5 waves/SIMD is still ample).
__global__ __launch_bounds__(256) void k_main(const float* __restrict__ f0,
                                              const float* __restrict__ amps,
                                              const float* __restrict__ ffq,
                                              const float* __restrict__ fbw,
                                              const float* __restrict__ fam,
                                              const float* __restrict__ initp,
                                              const double* __restrict__ part,
                                              float* __restrict__ out) {
    int b = blockIdx.y;
    int ch = blockIdx.x * 4 + (threadIdx.x >> 6);
    int lane = threadIdx.x & 63;
    if (ch >= NCH) return;
    int t0 = ch * CTS;
    int g0 = lane >> 2, j = lane & 3;
    const float4 f4z = make_float4(0.f, 0.f, 0.f, 0.f);
    const float* ab = amps + (size_t)b * NT * NH;

    // group-contiguous amp loads: instruction i reads float4 #(i*4+j)
    #define AMPLD(S0, S1, S2, S3, p)                                          \
        { const float4* rr =                                                  \
              (const float4*)(ab + (size_t)(t0 + (p) * 16 + g0) * NH);        \
          S0 = rr[j]; S1 = rr[4 + j]; S2 = rr[8 + j];                         \
          S3 = (j < 3) ? rr[12 + j] : f4z; }

    // ---- amp loads for passes 0,1 issue at cycle 0 ----
    float4 A0, A1, A2, A3, B0, B1, B2, B3;
    AMPLD(A0, A1, A2, A3, 0)
    AMPLD(B0, B1, B2, B3, 1)

    // ---- preamble (covers amp latency): prefix, lerp, scan ----
    const double* pb = part + b * NCH;
    double sl = 0.0;
    #pragma unroll
    for (int k = 0; k < 12; ++k) {
        int idx = k * 64 + lane;
        double v = (idx < NCH) ? pb[idx] : 0.0;
        if (idx < ch) sl += v;
    }
    #pragma unroll
    for (int off = 1; off < 64; off <<= 1)
        sl += __shfl_xor(sl, off, 64);

    double initrev = (double)initp[b] * (1.0 / TWO_PI);

    if (ch == 0) {                       // designated wave: final phase
        double sa = 0.0;
        #pragma unroll
        for (int k = 0; k < 12; ++k) {
            int idx = k * 64 + lane;
            if (idx < NCH) sa += pb[idx];
        }
        #pragma unroll
        for (int off = 1; off < 64; off <<= 1)
            sa += __shfl_xor(sa, off, 64);
        if (lane == 0) {
            double rv = sa * (1.0 / SRATE) + initrev;
            out[NB * NT + b] = (float)((rv - floor(rv)) * TWO_PI);
        }
    }

    // chunk-uniform fractional prefix (f64 once), then f32 in-chunk scan
    double pfrac = sl * (1.0 / SRATE) + initrev;
    float prefF = (float)(pfrac - floor(pfrac));     // [0,1), wave-uniform

    float f0v = f0[b * NT + t0 + lane];
    float incf = f0v;
    #pragma unroll
    for (int off = 1; off < 64; off <<= 1) {
        float n = __shfl_up(incf, off, 64);
        if (lane >= off) incf += n;
    }
    float rev_l = __builtin_amdgcn_fractf(prefF + incf * (1.0f / 24000.0f));
    float f0s_l = f0v * PSC;

    // formant lerp (lane = ts), 15 coeffs
    double srcd = (double)(t0 + lane) * (99.0 / 47999.0);
    int i0 = (int)srcd;
    if (i0 > NC - 2) i0 = NC - 2;
    float frac = (float)(srcd - (double)i0);
    float omf = 1.0f - frac;
    const float* Fq = ffq + (b * NC + i0) * NFMT;
    const float* Bw = fbw + (b * NC + i0) * NFMT;
    const float* Am = fam + (b * NC + i0) * NFMT;
    float fqs[NFMT], c1s[NFMT], c2s[NFMT];
    #pragma unroll
    for (int f = 0; f < NFMT; ++f) {
        float fqv = Fq[f] * omf + Fq[NFMT + f] * frac;
        float bwv = Bw[f] * omf + Bw[NFMT + f] * frac;
        float amv = Am[f] * omf + Am[NFMT + f] * frac;
        float bws = bwv * PSC;
        fqs[f] = fqv * PSC;
        c2s[f] = bws * bws;
        c1s[f] = amv * c2s[f];
    }

    // ---- one pass = 16 ts x 4 lanes; lane j: quads {4j+1..4} +0/16/32/48 ----
    auto do_pass = [&](int p, float4 q0, float4 q1, float4 q2, float4 q3) {
        int gp = (p << 4) + g0;
        float f0s   = __shfl(f0s_l, gp, 64);
        float rev_g = __shfl(rev_l, gp, 64);
        float fq[NFMT], c1[NFMT], c2[NFMT];
        #pragma unroll
        for (int f = 0; f < NFMT; ++f) {
            fq[f] = __shfl(fqs[f], gp, 64);
            c1[f] = __shfl(c1s[f], gp, 64);
            c2[f] = __shfl(c2s[f], gp, 64);
        }
        float hb = (float)(j << 2);
        auto sd = [&](float k) {
            return __builtin_amdgcn_sinf(
                __builtin_amdgcn_fractf((hb + k) * rev_g));
        };
        v2f s01 = {sd(1.0f),  sd(2.0f)};
        v2f s23 = {sd(3.0f),  sd(4.0f)};
        v2f s45 = {sd(17.0f), sd(18.0f)};
        v2f s67 = {sd(19.0f), sd(20.0f)};
        float c16 = __builtin_amdgcn_cosf(
            __builtin_amdgcn_fractf(16.0f * rev_g));    // cos(16*theta)
        v2f cv = {2.0f * c16, 2.0f * c16};
        v2f s89 = cv * s45 - s01;                       // (hb+33,34)
        v2f sAB = cv * s67 - s23;                       // (hb+35,36)
        v2f sCD = cv * s89 - s45;                       // (hb+49,50)
        v2f sEF = cv * sAB - s67;                       // (hb+51,52)
        v2f acc2 = {0.0f, 0.0f};
        auto pairf = [&](float h1, v2f sn, float a0, float a1) {
            v2f hfl = {h1, h1 + 1.0f};
            v2f hs = f0s * hfl;                         // f0*h * 2^-10
            v2f pN = {1.0f, 1.0f}, pD = {1.0f, 1.0f};
            #pragma unroll
            for (int f = 0; f < NFMT; ++f) {
                v2f d = hs - fq[f];
                v2f e = d * d + c2[f];
                pN *= e + c1[f];
                pD *= e;
            }
            float R = __builtin_amdgcn_rcpf(pD.x * pD.y);
            v2f fac = {pN.x * pD.y * R, pN.y * pD.x * R};
            v2f fm;
            fm.x = (hs.x < NYQS) ? fac.x : 0.0f;        // nyquist mask
            fm.y = (hs.y < NYQS) ? fac.y : 0.0f;
            v2f aa = {a0, a1};
            acc2 += (sn * aa) * fm;
        };
        pairf(hb + 1.0f,  s01, q0.x, q0.y);
        pairf(hb + 3.0f,  s23, q0.z, q0.w);
        pairf(hb + 17.0f, s45, q1.x, q1.y);
        pairf(hb + 19.0f, s67, q1.z, q1.w);
        pairf(hb + 33.0f, s89, q2.x, q2.y);
        pairf(hb + 35.0f, sAB, q2.z, q2.w);
        pairf(hb + 49.0f, sCD, q3.x, q3.y);
        pairf(hb + 51.0f, sEF, q3.z, q3.w);
        float acc = acc2.x + acc2.y;
        acc += __shfl_xor(acc, 1, 64);
        acc += __shfl_xor(acc, 2, 64);
        if (j == 0) {
            if (!(f0s > 0.0f)) acc = 0.0f;              // voiced mask
            out[b * NT + t0 + (p << 4) + g0] = acc;
        }
    };

    // ---- 4 passes, double-buffered prefetch ----
    do_pass(0, A0, A1, A2, A3);
    AMPLD(A0, A1, A2, A3, 2)
    do_pass(1, B0, B1, B2, B3);
    AMPLD(B0, B1, B2, B3, 3)
    do_pass(2, A0, A1, A2, A3);
    do_pass(3, B0, B1, B2, B3);
    #undef AMPLD
}

extern "C" void kernel_launch(void* const* d_in, const int* in_sizes, int n_in,
                              void* d_out, int out_size, void* d_ws, size_t ws_size,
                              hipStream_t stream) {
    const float* f0    = (const float*)d_in[0];
    const float* amps  = (const float*)d_in[1];
    const float* ffq   = (const float*)d_in[2];
    const float* fbw   = (const float*)d_in[3];
    const float* fam   = (const float*)d_in[4];
    const float* initp = (const float*)d_in[5];
    float* out = (float*)d_out;

    double* part = (double*)d_ws;                    // NB*NCH doubles (48 KB)

    dim3 gchunk((NCH + 3) / 4, NB);
    k_partial<<<gchunk, 256, 0, stream>>>(f0, part);
    k_main<<<gchunk, 256, 0, stream>>>(f0, amps, ffq, fbw, fam, initp, part, out);
}

// Round 15
// 32.487 us; speedup vs baseline: 4.0563x; 1.0110x over previous
//
#include <hip/hip_runtime.h>
#include <math.h>

#define SRATE   24000.0
#define NB      8
#define NT      48000
#define NH      60
#define NC      100
#define NFMT    5
#define CTS     64
#define NCH     (NT / CTS)       // 750 chunks per batch (= waves per batch)
#define TWO_PI  6.283185307179586476925286766559
#define PSC     (1.0f / 1024.0f) // exact 2^-10 prescale
#define NYQS    11.71875f        // 12000 * 2^-10

typedef float v2f __attribute__((ext_vector_type(2)));

// ---------------- kernel 1: per-chunk f0 sums (double) ----------------
__global__ __launch_bounds__(256) void k_partial(const float* __restrict__ f0,
                                                 double* __restrict__ part) {
    int b = blockIdx.y;
    int ch = blockIdx.x * 4 + (threadIdx.x >> 6);
    int lane = threadIdx.x & 63;
    if (ch < NCH) {
        int t = ch * CTS + lane;
        double q = (double)f0[b * NT + t];
        #pragma unroll
        for (int off = 32; off > 0; off >>= 1)
            q += __shfl_down(q, off, 64);
        if (lane == 0) part[b * NCH + ch] = q;
    }
}

// ---------------- kernel 2: main synthesis ----------------
// Anti-spill restructure (R13 diag: VGPR=64 + ~22MB/rep scratch writes).
// The per-lane coefficient bank (f0s, rev, 15 formant coeffs) moves to LDS:
// coef[wave][17][64]. Writes lane-contiguous; pass reads are 4-lane
// broadcasts at 16 distinct banks. Same-wave ds_write->ds_read needs no
// barrier. Kills ~17 permanently-live VGPRs/lane AND 17 bpermutes/pass.
__global__ __launch_bounds__(256) void k_main(const float* __restrict__ f0,
                                              const float* __restrict__ amps,
                                              const float* __restrict__ ffq,
                                              const float* __restrict__ fbw,
                                              const float* __restrict__ fam,
                                              const float* __restrict__ initp,
                                              const double* __restrict__ part,
                                              float* __restrict__ out) {
    int b = blockIdx.y;
    int wv = threadIdx.x >> 6;
    int ch = blockIdx.x * 4 + wv;
    int lane = threadIdx.x & 63;
    if (ch >= NCH) return;
    int t0 = ch * CTS;
    int g0 = lane >> 2, j = lane & 3;
    const float4 f4z = make_float4(0.f, 0.f, 0.f, 0.f);
    const float* ab = amps + (size_t)b * NT * NH;

    __shared__ float coef[4][17][64];   // per-wave coefficient bank

    // group-contiguous amp loads: instruction i reads float4 #(i*4+j)
    #define AMPLD(S0, S1, S2, S3, p)                                          \
        { const float4* rr =                                                  \
              (const float4*)(ab + (size_t)(t0 + (p) * 16 + g0) * NH);        \
          S0 = rr[j]; S1 = rr[4 + j]; S2 = rr[8 + j];                         \
          S3 = (j < 3) ? rr[12 + j] : f4z; }

    // ---- amp loads for passes 0,1 issue at cycle 0 ----
    float4 A0, A1, A2, A3, B0, B1, B2, B3;
    AMPLD(A0, A1, A2, A3, 0)
    AMPLD(B0, B1, B2, B3, 1)

    // ---- preamble (covers amp latency): prefix, scan, lerp -> LDS ----
    const double* pb = part + b * NCH;
    double sl = 0.0, sa = 0.0;
    #pragma unroll
    for (int k = 0; k < 12; ++k) {
        int idx = k * 64 + lane;
        double v = (idx < NCH) ? pb[idx] : 0.0;
        sa += v;
        if (idx < ch) sl += v;
    }
    #pragma unroll
    for (int off = 1; off < 64; off <<= 1) {
        sl += __shfl_xor(sl, off, 64);
        sa += __shfl_xor(sa, off, 64);
    }

    double initrev = (double)initp[b] * (1.0 / TWO_PI);

    if (ch == 0 && lane == 0) {          // designated wave: final phase
        double rv = sa * (1.0 / SRATE) + initrev;
        out[NB * NT + b] = (float)((rv - floor(rv)) * TWO_PI);
    }

    // chunk-uniform fractional prefix (f64 once), then f32 in-chunk scan
    double pfrac = sl * (1.0 / SRATE) + initrev;
    float prefF = (float)(pfrac - floor(pfrac));     // [0,1), wave-uniform

    float f0v = f0[b * NT + t0 + lane];
    float incf = f0v;
    #pragma unroll
    for (int off = 1; off < 64; off <<= 1) {
        float n = __shfl_up(incf, off, 64);
        if (lane >= off) incf += n;
    }
    coef[wv][0][lane] = f0v * PSC;
    coef[wv][1][lane] =
        __builtin_amdgcn_fractf(prefF + incf * (1.0f / 24000.0f));

    // formant lerp (lane = ts) -> LDS
    {
        double srcd = (double)(t0 + lane) * (99.0 / 47999.0);
        int i0 = (int)srcd;
        if (i0 > NC - 2) i0 = NC - 2;
        float frac = (float)(srcd - (double)i0);
        float omf = 1.0f - frac;
        const float* Fq = ffq + (b * NC + i0) * NFMT;
        const float* Bw = fbw + (b * NC + i0) * NFMT;
        const float* Am = fam + (b * NC + i0) * NFMT;
        #pragma unroll
        for (int f = 0; f < NFMT; ++f) {
            float fqv = Fq[f] * omf + Fq[NFMT + f] * frac;
            float bwv = Bw[f] * omf + Bw[NFMT + f] * frac;
            float amv = Am[f] * omf + Am[NFMT + f] * frac;
            float bws = bwv * PSC;
            float c2v = bws * bws;
            coef[wv][2 + f][lane]  = fqv * PSC;
            coef[wv][7 + f][lane]  = amv * c2v;
            coef[wv][12 + f][lane] = c2v;
        }
    }
    // same-wave LDS write->read: ordered by lgkmcnt, no barrier needed

    // ---- one pass = 16 ts x 4 lanes; lane j: quads {4j+1..4} +0/16/32/48 ----
    auto do_pass = [&](int p, float4 q0, float4 q1, float4 q2, float4 q3) {
        int gp = (p << 4) + g0;
        float f0s   = coef[wv][0][gp];
        float rev_g = coef[wv][1][gp];
        float hb = (float)(j << 2);
        auto sd = [&](float k) {
            return __builtin_amdgcn_sinf(
                __builtin_amdgcn_fractf((hb + k) * rev_g));
        };
        v2f s01 = {sd(1.0f),  sd(2.0f)};
        v2f s23 = {sd(3.0f),  sd(4.0f)};
        v2f s45 = {sd(17.0f), sd(18.0f)};
        v2f s67 = {sd(19.0f), sd(20.0f)};
        float c16 = __builtin_amdgcn_cosf(
            __builtin_amdgcn_fractf(16.0f * rev_g));    // cos(16*theta)
        v2f cv = {2.0f * c16, 2.0f * c16};
        v2f s89 = cv * s45 - s01;                       // (hb+33,34)
        v2f sAB = cv * s67 - s23;                       // (hb+35,36)
        v2f sCD = cv * s89 - s45;                       // (hb+49,50)
        v2f sEF = cv * sAB - s67;                       // (hb+51,52)
        v2f acc2 = {0.0f, 0.0f};
        auto pairf = [&](float h1, v2f sn, float a0, float a1) {
            v2f hfl = {h1, h1 + 1.0f};
            v2f hs = f0s * hfl;                         // f0*h * 2^-10
            v2f pN = {1.0f, 1.0f}, pD = {1.0f, 1.0f};
            #pragma unroll
            for (int f = 0; f < NFMT; ++f) {
                v2f d = hs - coef[wv][2 + f][gp];
                v2f e = d * d + coef[wv][12 + f][gp];
                pN *= e + coef[wv][7 + f][gp];
                pD *= e;
            }
            float R = __builtin_amdgcn_rcpf(pD.x * pD.y);
            v2f fac = {pN.x * pD.y * R, pN.y * pD.x * R};
            v2f fm;
            fm.x = (hs.x < NYQS) ? fac.x : 0.0f;        // nyquist mask
            fm.y = (hs.y < NYQS) ? fac.y : 0.0f;
            v2f aa = {a0, a1};
            acc2 += (sn * aa) * fm;
        };
        pairf(hb + 1.0f,  s01, q0.x, q0.y);
        pairf(hb + 3.0f,  s23, q0.z, q0.w);
        pairf(hb + 17.0f, s45, q1.x, q1.y);
        pairf(hb + 19.0f, s67, q1.z, q1.w);
        pairf(hb + 33.0f, s89, q2.x, q2.y);
        pairf(hb + 35.0f, sAB, q2.z, q2.w);
        pairf(hb + 49.0f, sCD, q3.x, q3.y);
        pairf(hb + 51.0f, sEF, q3.z, q3.w);
        float acc = acc2.x + acc2.y;
        acc += __shfl_xor(acc, 1, 64);
        acc += __shfl_xor(acc, 2, 64);
        if (j == 0) {
            if (!(f0s > 0.0f)) acc = 0.0f;              // voiced mask
            out[b * NT + t0 + (p << 4) + g0] = acc;
        }
    };

    // ---- 4 passes, double-buffered prefetch ----
    do_pass(0, A0, A1, A2, A3);
    AMPLD(A0, A1, A2, A3, 2)
    do_pass(1, B0, B1, B2, B3);
    AMPLD(B0, B1, B2, B3, 3)
    do_pass(2, A0, A1, A2, A3);
    do_pass(3, B0, B1, B2, B3);
    #undef AMPLD
}

extern "C" void kernel_launch(void* const* d_in, const int* in_sizes, int n_in,
                              void* d_out, int out_size, void* d_ws, size_t ws_size,
                              hipStream_t stream) {
    const float* f0    = (const float*)d_in[0];
    const float* amps  = (const float*)d_in[1];
    const float* ffq   = (const float*)d_in[2];
    const float* fbw   = (const float*)d_in[3];
    const float* fam   = (const float*)d_in[4];
    const float* initp = (const float*)d_in[5];
    float* out = (float*)d_out;

    double* part = (double*)d_ws;                    // NB*NCH doubles (48 KB)

    dim3 gchunk((NCH + 3) / 4, NB);
    k_partial<<<gchunk, 256, 0, stream>>>(f0, part);
    k_main<<<gchunk, 256, 0, stream>>>(f0, amps, ffq, fbw, fam, initp, part, out);
}